// Round 8
// baseline (312.625 us; speedup 1.0000x reference)
//
#include <hip/hip_runtime.h>

// ElectrostaticEnergyLayer: per-pair shielded/switched Coulomb energy,
// scatter-added to atoms by idx_i.
//
// R16: pipeline fission of ee_bin. Six rounds showed the fused kernel's
// 134us floor is structural: the gather/compute phase wants occupancy
// (latency hiding) while the LDS-staging phase wants LDS capacity (38.9KB
// -> measured 38% occupancy); fused, each throttles the other. Split:
//   K1 ee_radial: no LDS, 256-thr, full-occupancy streaming -- reads Dij +
//      idx_j, gathers Qj, writes w16 = rn(Qj*R(d)*2^13) (int16; -32768
//      sentinel = d>10). 168MB traffic, gather latency hidden by TLP.
//   K2 ee_binw: R15's ee_bin with phase A = coalesced idx_i + w16 loads
//      (no gather, no radial). v = w16<<6 feeds the existing 2^19 fixed-
//      point pipeline (extra quant err ~5e-3/atom vs 0.33 threshold).
// Workspace tiering (ws_size never probed beyond 67.1MB): split needs
// ~96MB; if unavailable, fall to the R15-exact fast path (proven 272.8us),
// then to global-atomic fallbacks. Zero-downside experiment.
// Established: global atomics are memory-side on gfx950 (R12, 432MB
// WRITE_SIZE); rest ~122us is fixed harness overhead (R12 3-dispatch
// control); bank-conflict/pad taxes are latency-hidden (R14/R15).

#define KEHALF 7.199822675975274f
#define NB    128            // buckets
#define BSH   11             // atoms per bucket = 2048
#define BMASK 2047
#define CAP   126976         // entries per bucket region (list = 62 MiB)
#define CURSTRIDE 16         // cursors 64 B apart
#define SCH   2              // phase-2 chunks per bucket
#define SCAP  72             // LDS staging slots per bucket per block
#define SSTR  73             // stage stride (coprime with 32 banks)
#define VSCALE 524288.0f     // 2^19
#define VINV   (1.0f / 524288.0f)
#define WSH   6              // w16 -> v19 shift (2^13 -> 2^19)
#define WSCALE 8192.0f       // 2^13
#define WSENT  (-32768)      // invalid-pair sentinel
#define P1B   512            // binning block threads
#define P1PAIRS 8192         // pairs per binning block (512 thr x 16)
#define RADB  256            // ee_radial block threads
#define RADPAIRS 2048        // pairs per ee_radial block (256 thr x 8)

// radial factor R(d) via fast rcp/rsq: E = KEHALF * Qi * Qj * R(d)
__device__ __forceinline__ float radial_fast(float d) {
    float d2p1 = d * d + 1.0f;
    float rsq  = __builtin_amdgcn_rsqf(d2p1);          // 1/sqrt(d^2+1)
    float x    = 0.5f * d;
    float sw   = (x < 1.0f) ? 1.0f - x * x * x * (x * (6.0f * x - 15.0f) + 10.0f)
                            : 0.0f;
    float Eo = __builtin_amdgcn_rcpf(d) + d * 0.01f - 0.2f;
    float Es = rsq * (1.0f + 0.01f * d2p1) - 0.2f;     // 1/dsh + dsh/100
    return sw * Es + (1.0f - sw) * Eo;
}

// ---------------- K1: streaming radial+gather, full occupancy -------------
__global__ __launch_bounds__(RADB) void ee_radial(
    const float* __restrict__ Dij,
    const float* __restrict__ Qa,
    const int*   __restrict__ idx_j,
    short*       __restrict__ w)        // P int16 outputs
{
    long blockBase = (long)blockIdx.x * RADPAIRS;
    int tid = threadIdx.x;
#pragma unroll
    for (int g = 0; g < 2; ++g) {
        long o = blockBase + (long)(g * RADB + tid) * 4;
        int4   j4 = *reinterpret_cast<const int4*>(idx_j + o);
        float qj0 = Qa[j4.x], qj1 = Qa[j4.y], qj2 = Qa[j4.z], qj3 = Qa[j4.w];
        float4 d4 = *reinterpret_cast<const float4*>(Dij + o);
        float dd[4] = {d4.x, d4.y, d4.z, d4.w};
        float qq[4] = {qj0, qj1, qj2, qj3};
        short s[4];
#pragma unroll
        for (int k = 0; k < 4; ++k) {
            float wf = qq[k] * radial_fast(dd[k]) * WSCALE;
            wf = fminf(fmaxf(wf, -32000.0f), 32000.0f);    // v_med3-style clamp
            int v = __float2int_rn(wf);
            s[k] = (dd[k] <= 10.0f) ? (short)v : (short)WSENT;
        }
        short4 sv = {s[0], s[1], s[2], s[3]};
        *reinterpret_cast<short4*>(w + o) = sv;             // 8B coalesced
    }
}

// ---------------- K2: binning from precomputed w16 (no gather) ------------
__global__ __launch_bounds__(P1B, 4) void ee_binw(
    const short* __restrict__ w,
    const float* __restrict__ Qa,       // spill path only
    const int*   __restrict__ idx_i,
    unsigned int* __restrict__ list,
    unsigned int* __restrict__ gcur,
    float*        __restrict__ out)
{
    __shared__ unsigned int stage[NB * SSTR];
    __shared__ int lcur[NB + 32];
    __shared__ int gofs[NB];
    int tid = threadIdx.x;
    if (tid < NB + 32) lcur[tid] = 0;
    __syncthreads();

    long blockBase = (long)blockIdx.x * P1PAIRS;

    unsigned int EN[16];
    int          BK[16];
    int trash = NB + (tid & 31);
#pragma unroll
    for (int g = 0; g < 4; ++g) {
        long o = blockBase + (long)(g * P1B + tid) * 4;
        int4   i4 = *reinterpret_cast<const int4*>(idx_i + o);
        short4 w4 = *reinterpret_cast<const short4*>(w + o);
        short ws[4] = {w4.x, w4.y, w4.z, w4.w};
        int   ii[4] = {i4.x, i4.y, i4.z, i4.w};
#pragma unroll
        for (int k = 0; k < 4; ++k) {
            int m = g * 4 + k;
            int v = ((int)ws[k]) << WSH;
            EN[m] = ((unsigned int)(ii[k] & BMASK) << 21) |
                    ((unsigned int)v & 0x1FFFFFu);
            BK[m] = (ws[k] != WSENT) ? (ii[k] >> BSH) : trash;
        }
    }

    // B1: 16 unconditional ds_add_rtn (trash lanes spread per-bank)
    int SL[16];
#pragma unroll
    for (int m = 0; m < 16; ++m)
        SL[m] = atomicAdd(&lcur[BK[m]], 1);

    // B2: conditional ds_writes + rare decode-spill
#pragma unroll
    for (int m = 0; m < 16; ++m) {
        if (BK[m] < NB) {
            if (SL[m] < SCAP) {
                stage[BK[m] * SSTR + SL[m]] = EN[m];
            } else {
                int atom = (BK[m] << BSH) | (int)(EN[m] >> 21);
                int v    = ((int)(EN[m] << 11)) >> 11;
                atomicAdd(out + atom, KEHALF * Qa[atom] * ((float)v * VINV));
            }
        }
    }
    __syncthreads();

    if (tid < NB) {
        int n = lcur[tid];
        if (n > SCAP) n = SCAP;
        lcur[tid] = n;
        int padded = (n + 3) & ~3;
        gofs[tid] = (int)atomicAdd(&gcur[tid * CURSTRIDE], (unsigned int)padded);
    }
    __syncthreads();

    int wave = tid >> 6, lane = tid & 63;
    for (int b = wave; b < NB; b += (P1B / 64)) {
        int n = lcur[b];
        int padded = (n + 3) & ~3;
        int go = gofs[b];
        long rb = (long)b * CAP;
        for (int i = lane; i < padded; i += 64) {
            unsigned int val = (i < n) ? stage[b * SSTR + i]
                                       : ((unsigned int)(i & BMASK) << 21);
            int pos = go + i;
            if (pos < CAP)
                list[rb + pos] = val;
        }
    }
}

// ---------------- R15-exact fused binning (middle tier) -------------------
__global__ __launch_bounds__(P1B, 4) void ee_bin(
    const float* __restrict__ Dij,
    const float* __restrict__ Qa,
    const int*   __restrict__ idx_i,
    const int*   __restrict__ idx_j,
    unsigned int* __restrict__ list,
    unsigned int* __restrict__ gcur,
    float*        __restrict__ out)
{
    __shared__ unsigned int stage[NB * SSTR];
    __shared__ int lcur[NB + 32];
    __shared__ int gofs[NB];
    int tid = threadIdx.x;
    if (tid < NB + 32) lcur[tid] = 0;
    __syncthreads();

    long blockBase = (long)blockIdx.x * P1PAIRS;

    unsigned int EN[16];
    int          BK[16];
    int trash = NB + (tid & 31);
#pragma unroll
    for (int g = 0; g < 4; ++g) {
        long o = blockBase + ((long)(g * P1B + tid)) * 4;
        int4 j4 = *reinterpret_cast<const int4*>(idx_j + o);
        float qj0 = Qa[j4.x], qj1 = Qa[j4.y], qj2 = Qa[j4.z], qj3 = Qa[j4.w];
        float4 d4 = *reinterpret_cast<const float4*>(Dij + o);
        int4   i4 = *reinterpret_cast<const int4*>(idx_i + o);
        float dd[4] = {d4.x, d4.y, d4.z, d4.w};
        float qq[4] = {qj0, qj1, qj2, qj3};
        int   ii[4] = {i4.x, i4.y, i4.z, i4.w};
#pragma unroll
        for (int k = 0; k < 4; ++k) {
            int m = g * 4 + k;
            float d = dd[k];
            float ww = qq[k] * radial_fast(d);
            int v = __float2int_rn(ww * VSCALE);
            EN[m] = ((unsigned int)(ii[k] & BMASK) << 21) |
                    ((unsigned int)v & 0x1FFFFFu);
            BK[m] = (d <= 10.0f) ? (ii[k] >> BSH) : trash;
        }
    }

    int SL[16];
#pragma unroll
    for (int m = 0; m < 16; ++m)
        SL[m] = atomicAdd(&lcur[BK[m]], 1);

#pragma unroll
    for (int m = 0; m < 16; ++m) {
        if (BK[m] < NB) {
            if (SL[m] < SCAP) {
                stage[BK[m] * SSTR + SL[m]] = EN[m];
            } else {
                int atom = (BK[m] << BSH) | (int)(EN[m] >> 21);
                int v    = ((int)(EN[m] << 11)) >> 11;
                atomicAdd(out + atom, KEHALF * Qa[atom] * ((float)v * VINV));
            }
        }
    }
    __syncthreads();

    if (tid < NB) {
        int n = lcur[tid];
        if (n > SCAP) n = SCAP;
        lcur[tid] = n;
        int padded = (n + 3) & ~3;
        gofs[tid] = (int)atomicAdd(&gcur[tid * CURSTRIDE], (unsigned int)padded);
    }
    __syncthreads();

    int wave = tid >> 6, lane = tid & 63;
    for (int b = wave; b < NB; b += (P1B / 64)) {
        int n = lcur[b];
        int padded = (n + 3) & ~3;
        int go = gofs[b];
        long rb = (long)b * CAP;
        for (int i = lane; i < padded; i += 64) {
            unsigned int val = (i < n) ? stage[b * SSTR + i]
                                       : ((unsigned int)(i & BMASK) << 21);
            int pos = go + i;
            if (pos < CAP)
                list[rb + pos] = val;
        }
    }
}

// ---------------- Phase 2: per-bucket-chunk LDS int accumulation ----------
__global__ __launch_bounds__(512) void ee_acc(
    const unsigned int* __restrict__ list,
    const unsigned int* __restrict__ gcur,
    int* __restrict__ partials)          // [NB*SCH][2048]
{
    __shared__ int acc[1 << BSH];
    int b = blockIdx.x / SCH;
    int s = blockIdx.x % SCH;
    int t = threadIdx.x;
#pragma unroll
    for (int r = 0; r < (1 << BSH) / 512; ++r) acc[t + r * 512] = 0;
    __syncthreads();

    int n = (int)gcur[b * CURSTRIDE];
    if (n > CAP) n = CAP;
    int nq = n >> 2;
    int per = (nq + SCH - 1) / SCH;
    int q0 = s * per;
    int q1 = q0 + per; if (q1 > nq) q1 = nq;

    const uint4* lp4 = reinterpret_cast<const uint4*>(list + (long)b * CAP);
    for (int q = q0 + t; q < q1; q += 512) {
        uint4 u4 = lp4[q];
        unsigned int us[4] = {u4.x, u4.y, u4.z, u4.w};
#pragma unroll
        for (int k = 0; k < 4; ++k) {
            unsigned int u = us[k];
            int li = (int)(u >> 21);
            int v  = ((int)(u << 11)) >> 11;
            atomicAdd(&acc[li], v);
        }
    }
    __syncthreads();

    int* pp = partials + ((long)b * SCH + s) * (1 << BSH);
#pragma unroll
    for (int r = 0; r < (1 << BSH) / 512; ++r) pp[t + r * 512] = acc[t + r * 512];
}

// ---------------- Phase 3: combine partials, apply KEHALF*Qi, add spill ----
__global__ __launch_bounds__(256) void ee_final(
    const int* __restrict__ partials,
    const float* __restrict__ Qa,
    float* __restrict__ out, int nAtoms)
{
    int q = blockIdx.x * blockDim.x + threadIdx.x;
    int n4 = nAtoms >> 2;
    if (q >= n4) return;
    int a0 = q << 2;
    int b  = a0 >> BSH;
    int li = a0 & BMASK;
    long base = (long)(b * SCH) * (1 << BSH) + li;
    int4 s = {0, 0, 0, 0};
#pragma unroll
    for (int r = 0; r < SCH; ++r) {
        int4 p = *reinterpret_cast<const int4*>(partials + base + (long)r * (1 << BSH));
        s.x += p.x; s.y += p.y; s.z += p.z; s.w += p.w;
    }
    float4 qv = reinterpret_cast<const float4*>(Qa)[q];
    float4 sp = reinterpret_cast<const float4*>(out)[q];
    float4 o;
    o.x = KEHALF * qv.x * ((float)s.x * VINV) + sp.x;
    o.y = KEHALF * qv.y * ((float)s.y * VINV) + sp.y;
    o.z = KEHALF * qv.z * ((float)s.z * VINV) + sp.z;
    o.w = KEHALF * qv.w * ((float)s.w * VINV) + sp.w;
    reinterpret_cast<float4*>(out)[q] = o;
}

// ---------------- Fallback: int fixed-point global atomics (R3) --------
#define FP_SCALE 4194304.0f
#define FP_INV   (1.0f / 4194304.0f)

__device__ __forceinline__ float radial_exact(float d) {
    float dsh = sqrtf(d * d + 1.0f);
    float x   = 0.5f * d;
    float sw  = (x < 1.0f) ? 1.0f - x * x * x * (x * (6.0f * x - 15.0f) + 10.0f)
                           : 0.0f;
    float Eo = 1.0f / d   + d   * 0.01f - 0.2f;
    float Es = 1.0f / dsh + dsh * 0.01f - 0.2f;
    return sw * Es + (1.0f - sw) * Eo;
}

__global__ __launch_bounds__(256) void ee_pair_fix(
    const float* __restrict__ Dij,
    const float* __restrict__ Qa,
    const int*   __restrict__ idx_i,
    const int*   __restrict__ idx_j,
    int*         __restrict__ acc,
    int P)
{
    long base = ((long)blockIdx.x * blockDim.x + threadIdx.x) * 4;
    if (base >= P) return;
    float4 d4 = *reinterpret_cast<const float4*>(Dij + base);
    int4   i4 = *reinterpret_cast<const int4*>(idx_i + base);
    int4   j4 = *reinterpret_cast<const int4*>(idx_j + base);
    float D[4]  = {d4.x, d4.y, d4.z, d4.w};
    int   ii[4] = {i4.x, i4.y, i4.z, i4.w};
    int   jj[4] = {j4.x, j4.y, j4.z, j4.w};
#pragma unroll
    for (int k = 0; k < 4; ++k) {
        float d = D[k];
        if (d > 10.0f) continue;
        float e = KEHALF * Qa[ii[k]] * Qa[jj[k]] * radial_exact(d);
        atomicAdd(acc + ii[k], __float2int_rn(e * FP_SCALE));
    }
}

__global__ __launch_bounds__(256) void ee_convert(
    const int* __restrict__ acc, float* __restrict__ out, int nAtoms)
{
    int n4 = nAtoms >> 2;
    int q = blockIdx.x * blockDim.x + threadIdx.x;
    if (q >= n4) return;
    int4 a = reinterpret_cast<const int4*>(acc)[q];
    float4 o;
    o.x = (float)a.x * FP_INV;
    o.y = (float)a.y * FP_INV;
    o.z = (float)a.z * FP_INV;
    o.w = (float)a.w * FP_INV;
    reinterpret_cast<float4*>(out)[q] = o;
}

__global__ __launch_bounds__(256) void ee_pair_direct(
    const float* __restrict__ Dij,
    const float* __restrict__ Qa,
    const int*   __restrict__ idx_i,
    const int*   __restrict__ idx_j,
    float*       __restrict__ out,
    int P)
{
    long t = (long)blockIdx.x * blockDim.x + threadIdx.x;
    if (t >= P) return;
    float d = Dij[t];
    if (d > 10.0f) return;
    atomicAdd(out + idx_i[t], KEHALF * Qa[idx_i[t]] * Qa[idx_j[t]] * radial_exact(d));
}

extern "C" void kernel_launch(void* const* d_in, const int* in_sizes, int n_in,
                              void* d_out, int out_size, void* d_ws, size_t ws_size,
                              hipStream_t stream) {
    const float* Dij   = (const float*)d_in[0];
    const float* Qa    = (const float*)d_in[1];
    const int*   idx_i = (const int*)d_in[2];
    const int*   idx_j = (const int*)d_in[3];
    float*       out   = (float*)d_out;

    int P      = in_sizes[0];
    int nAtoms = in_sizes[1];

    size_t listBytes = (size_t)NB * CAP * sizeof(unsigned int);          // 62 MiB
    size_t partBytes = (size_t)NB * SCH * (1 << BSH) * sizeof(int);      // 2 MiB
    size_t curBytes  = (size_t)NB * CURSTRIDE * sizeof(unsigned int);    // 8 KiB
    size_t wBytes    = (size_t)P * sizeof(short);                        // 32 MiB
    size_t baseBytes = listBytes + partBytes + curBytes;

    if (ws_size >= baseBytes + wBytes &&
        nAtoms == NB * (1 << BSH) && (P % P1PAIRS) == 0 &&
        (P % RADPAIRS) == 0) {
        // ---- split pipeline (R16) ----
        unsigned int* list = (unsigned int*)d_ws;
        int*          part = (int*)((char*)d_ws + listBytes);
        unsigned int* gcur = (unsigned int*)((char*)d_ws + listBytes + partBytes);
        short*        wbuf = (short*)((char*)d_ws + baseBytes);
        hipMemsetAsync(gcur, 0, curBytes, stream);
        hipMemsetAsync(out, 0, (size_t)out_size * sizeof(float), stream);
        ee_radial<<<P / RADPAIRS, RADB, 0, stream>>>(Dij, Qa, idx_j, wbuf);
        ee_binw<<<P / P1PAIRS, P1B, 0, stream>>>(wbuf, Qa, idx_i, list, gcur, out);
        ee_acc<<<NB * SCH, 512, 0, stream>>>(list, gcur, part);
        ee_final<<<(nAtoms / 4 + 255) / 256, 256, 0, stream>>>(part, Qa, out, nAtoms);
    } else if (ws_size >= baseBytes &&
               nAtoms == NB * (1 << BSH) && (P % P1PAIRS) == 0) {
        // ---- R15-exact fused pipeline (proven 272.8us) ----
        unsigned int* list = (unsigned int*)d_ws;
        int*          part = (int*)((char*)d_ws + listBytes);
        unsigned int* gcur = (unsigned int*)((char*)d_ws + listBytes + partBytes);
        hipMemsetAsync(gcur, 0, curBytes, stream);
        hipMemsetAsync(out, 0, (size_t)out_size * sizeof(float), stream);
        ee_bin<<<P / P1PAIRS, P1B, 0, stream>>>(Dij, Qa, idx_i, idx_j, list, gcur, out);
        ee_acc<<<NB * SCH, 512, 0, stream>>>(list, gcur, part);
        ee_final<<<(nAtoms / 4 + 255) / 256, 256, 0, stream>>>(part, Qa, out, nAtoms);
    } else if (ws_size >= (size_t)nAtoms * sizeof(int) &&
               (nAtoms & 3) == 0 && (P & 3) == 0) {
        int* acc = (int*)d_ws;
        hipMemsetAsync(acc, 0, (size_t)nAtoms * sizeof(int), stream);
        int grid = (P / 4 + 255) / 256;
        ee_pair_fix<<<grid, 256, 0, stream>>>(Dij, Qa, idx_i, idx_j, acc, P);
        ee_convert<<<(nAtoms / 4 + 255) / 256, 256, 0, stream>>>(acc, out, nAtoms);
    } else {
        hipMemsetAsync(out, 0, (size_t)out_size * sizeof(float), stream);
        int grid = (P + 255) / 256;
        ee_pair_direct<<<grid, 256, 0, stream>>>(Dij, Qa, idx_i, idx_j, out, P);
    }
}

// Round 9
// 271.009 us; speedup vs baseline: 1.1536x; 1.1536x over previous
//
#include <hip/hip_runtime.h>

// ElectrostaticEnergyLayer: per-pair shielded/switched Coulomb energy,
// scatter-added to atoms by idx_i.
//
// R17 = R15 launcher/pipeline (proven 272.8us) with ee_bin phase A
// restructured for memory-level parallelism.
//  - R16 diagnostic: ee_radial (gather+stream only, no LDS) = 116us of the
//    fused 134us -- at VGPR 32/44 the per-group {j4 load -> wait -> 4
//    gathers -> wait -> compute} chain serializes ~8 round-trips/thread;
//    no pipe is >20% busy. The LDS machinery costs only ~18us fused.
//  - Fix: issue ALL 28 loads (4 j4, 16 Qa gathers right after their j4,
//    4 d4, 4 i4) before ANY compute, then __builtin_amdgcn_sched_barrier(0)
//    so hipcc cannot sink loads into the compute block (R9 failed exactly
//    this way without the fence). Critical path ~2 round-trips instead of 8.
//  - B1/B2/copy-out/acc/final unchanged from R15 (bank-spread trash
//    counters, stride-73 stage, pad-4 copy-out).
// Established: global atomics are memory-side on gfx950 (R12: 432MB
// WRITE_SIZE) => binned-LDS pipeline mandatory; rest ~120us is fixed
// harness overhead (R12 3-dispatch control); bank-conflict/pad taxes are
// latency-hidden (R14/R15); fission costs more than it saves (R16).
// Fast math: v_rcp/v_rsq builtins; Es = rsq*(1+0.01*(d^2+1))-0.2 (no sqrt,
// no div; rel err ~1e-5 vs 0.33 abs threshold).

#define KEHALF 7.199822675975274f
#define NB    128            // buckets
#define BSH   11             // atoms per bucket = 2048
#define BMASK 2047
#define CAP   126976         // entries per bucket region (list = 62 MiB)
#define CURSTRIDE 16         // cursors 64 B apart
#define SCH   2              // phase-2 chunks per bucket
#define SCAP  72             // LDS staging slots per bucket per block
#define SSTR  73             // stage stride (coprime with 32 banks)
#define VSCALE 524288.0f     // 2^19; |Qj*R| <= ~1.6 -> |v| < 2^20
#define VINV   (1.0f / 524288.0f)
#define P1B   512            // phase-1 block threads
#define P1PAIRS 8192         // pairs per phase-1 block (512 thr x 16)

// radial factor R(d) via fast rcp/rsq: E = KEHALF * Qi * Qj * R(d)
__device__ __forceinline__ float radial_fast(float d) {
    float d2p1 = d * d + 1.0f;
    float rsq  = __builtin_amdgcn_rsqf(d2p1);          // 1/sqrt(d^2+1)
    float x    = 0.5f * d;
    float sw   = (x < 1.0f) ? 1.0f - x * x * x * (x * (6.0f * x - 15.0f) + 10.0f)
                            : 0.0f;
    float Eo = __builtin_amdgcn_rcpf(d) + d * 0.01f - 0.2f;
    float Es = rsq * (1.0f + 0.01f * d2p1) - 0.2f;     // 1/dsh + dsh/100
    return sw * Es + (1.0f - sw) * Eo;
}

// ---------------- Phase 1: LDS-staged binning, MLP-batched loads ----------
__global__ __launch_bounds__(P1B, 4) void ee_bin(
    const float* __restrict__ Dij,
    const float* __restrict__ Qa,
    const int*   __restrict__ idx_i,
    const int*   __restrict__ idx_j,
    unsigned int* __restrict__ list,    // NB * CAP packed entries
    unsigned int* __restrict__ gcur,    // NB cursors, stride CURSTRIDE
    float*        __restrict__ out)     // spill target (pre-zeroed)
{
    __shared__ unsigned int stage[NB * SSTR];   // 36.5 KiB
    __shared__ int lcur[NB + 32];               // +32 per-bank trash counters
    __shared__ int gofs[NB];
    int tid = threadIdx.x;
    if (tid < NB + 32) lcur[tid] = 0;
    __syncthreads();

    long blockBase = (long)blockIdx.x * P1PAIRS;
    long o0 = blockBase + (long)(0 * P1B + tid) * 4;
    long o1 = blockBase + (long)(1 * P1B + tid) * 4;
    long o2 = blockBase + (long)(2 * P1B + tid) * 4;
    long o3 = blockBase + (long)(3 * P1B + tid) * 4;

    // ---- phase A-load: ALL 28 loads issued before any compute ----
    // j-index streams first, gathers immediately after (issue as j4 lands),
    // then the independent d/i streams fill the latency shadow.
    int4 j40 = *reinterpret_cast<const int4*>(idx_j + o0);
    int4 j41 = *reinterpret_cast<const int4*>(idx_j + o1);
    int4 j42 = *reinterpret_cast<const int4*>(idx_j + o2);
    int4 j43 = *reinterpret_cast<const int4*>(idx_j + o3);
    float QJ[16];
    QJ[0]  = Qa[j40.x]; QJ[1]  = Qa[j40.y]; QJ[2]  = Qa[j40.z]; QJ[3]  = Qa[j40.w];
    QJ[4]  = Qa[j41.x]; QJ[5]  = Qa[j41.y]; QJ[6]  = Qa[j41.z]; QJ[7]  = Qa[j41.w];
    QJ[8]  = Qa[j42.x]; QJ[9]  = Qa[j42.y]; QJ[10] = Qa[j42.z]; QJ[11] = Qa[j42.w];
    QJ[12] = Qa[j43.x]; QJ[13] = Qa[j43.y]; QJ[14] = Qa[j43.z]; QJ[15] = Qa[j43.w];
    float4 d40 = *reinterpret_cast<const float4*>(Dij + o0);
    float4 d41 = *reinterpret_cast<const float4*>(Dij + o1);
    float4 d42 = *reinterpret_cast<const float4*>(Dij + o2);
    float4 d43 = *reinterpret_cast<const float4*>(Dij + o3);
    int4 i40 = *reinterpret_cast<const int4*>(idx_i + o0);
    int4 i41 = *reinterpret_cast<const int4*>(idx_i + o1);
    int4 i42 = *reinterpret_cast<const int4*>(idx_i + o2);
    int4 i43 = *reinterpret_cast<const int4*>(idx_i + o3);
    // fence: compute below must not be hoisted above / loads not sunk below
    __builtin_amdgcn_sched_barrier(0);

    // ---- phase A-compute: pure VALU on resident registers ----
    float DD[16] = {d40.x, d40.y, d40.z, d40.w,  d41.x, d41.y, d41.z, d41.w,
                    d42.x, d42.y, d42.z, d42.w,  d43.x, d43.y, d43.z, d43.w};
    int   II[16] = {i40.x, i40.y, i40.z, i40.w,  i41.x, i41.y, i41.z, i41.w,
                    i42.x, i42.y, i42.z, i42.w,  i43.x, i43.y, i43.z, i43.w};
    unsigned int EN[16];   // (li << 21) | (v & 0x1FFFFF)
    int          BK[16];   // bucket, or NB+(tid&31) trash slot if d > 10
    int trash = NB + (tid & 31);
#pragma unroll
    for (int m = 0; m < 16; ++m) {
        float d = DD[m];
        float w = QJ[m] * radial_fast(d);                   // deferred Qi
        int v = __float2int_rn(w * VSCALE);
        EN[m] = ((unsigned int)(II[m] & BMASK) << 21) |
                ((unsigned int)v & 0x1FFFFFu);
        BK[m] = (d <= 10.0f) ? (II[m] >> BSH) : trash;      // cndmask, no branch
    }

    // ---- phase B1: 16 unconditional ds_add_rtn, back-to-back ----
    int SL[16];
#pragma unroll
    for (int m = 0; m < 16; ++m)
        SL[m] = atomicAdd(&lcur[BK[m]], 1);

    // ---- phase B2: conditional ds_writes + rare decode-spill ----
#pragma unroll
    for (int m = 0; m < 16; ++m) {
        if (BK[m] < NB) {
            if (SL[m] < SCAP) {
                stage[BK[m] * SSTR + SL[m]] = EN[m];
            } else {
                // rare (~900/launch at SCAP=72): quantized spill, no re-gather
                int atom = (BK[m] << BSH) | (int)(EN[m] >> 21);
                int v    = ((int)(EN[m] << 11)) >> 11;
                atomicAdd(out + atom, KEHALF * Qa[atom] * ((float)v * VINV));
            }
        }
    }
    __syncthreads();

    // one padded (4-entry = 16 B multiple) reservation per (block, bucket)
    if (tid < NB) {
        int n = lcur[tid];
        if (n > SCAP) n = SCAP;
        lcur[tid] = n;                          // clamp for copy-out
        int padded = (n + 3) & ~3;
        gofs[tid] = (int)atomicAdd(&gcur[tid * CURSTRIDE], (unsigned int)padded);
    }
    __syncthreads();

    // coalesced copy-out: wave w handles buckets w, w+8, ...
    int wave = tid >> 6, lane = tid & 63;
    for (int b = wave; b < NB; b += (P1B / 64)) {
        int n = lcur[b];
        int padded = (n + 3) & ~3;
        int go = gofs[b];
        long rb = (long)b * CAP;
        for (int i = lane; i < padded; i += 64) {
            // pad entries: v=0, li spread (no acc[0] hammering in phase 2)
            unsigned int val = (i < n) ? stage[b * SSTR + i]
                                       : ((unsigned int)(i & BMASK) << 21);
            int pos = go + i;
            if (pos < CAP)                       // statistical hard guard
                list[rb + pos] = val;
        }
    }
}

// ---------------- Phase 2: per-bucket-chunk LDS int accumulation ----------
__global__ __launch_bounds__(512) void ee_acc(
    const unsigned int* __restrict__ list,
    const unsigned int* __restrict__ gcur,
    int* __restrict__ partials)          // [NB*SCH][2048]
{
    __shared__ int acc[1 << BSH];
    int b = blockIdx.x / SCH;
    int s = blockIdx.x % SCH;
    int t = threadIdx.x;
#pragma unroll
    for (int r = 0; r < (1 << BSH) / 512; ++r) acc[t + r * 512] = 0;
    __syncthreads();

    int n = (int)gcur[b * CURSTRIDE];    // padded total, multiple of 4
    if (n > CAP) n = CAP;
    int nq = n >> 2;                     // uint4 count
    int per = (nq + SCH - 1) / SCH;
    int q0 = s * per;
    int q1 = q0 + per; if (q1 > nq) q1 = nq;

    const uint4* lp4 = reinterpret_cast<const uint4*>(list + (long)b * CAP);
    for (int q = q0 + t; q < q1; q += 512) {
        uint4 u4 = lp4[q];
        unsigned int us[4] = {u4.x, u4.y, u4.z, u4.w};
#pragma unroll
        for (int k = 0; k < 4; ++k) {
            unsigned int u = us[k];
            int li = (int)(u >> 21);
            int v  = ((int)(u << 11)) >> 11;   // sign-extend 21-bit payload
            atomicAdd(&acc[li], v);            // native ds_add_u32
        }
    }
    __syncthreads();

    int* pp = partials + ((long)b * SCH + s) * (1 << BSH);
#pragma unroll
    for (int r = 0; r < (1 << BSH) / 512; ++r) pp[t + r * 512] = acc[t + r * 512];
}

// ---------------- Phase 3: combine partials, apply KEHALF*Qi, add spill ----
__global__ __launch_bounds__(256) void ee_final(
    const int* __restrict__ partials,
    const float* __restrict__ Qa,
    float* __restrict__ out, int nAtoms)
{
    int q = blockIdx.x * blockDim.x + threadIdx.x;      // one int4 per thread
    int n4 = nAtoms >> 2;
    if (q >= n4) return;
    int a0 = q << 2;
    int b  = a0 >> BSH;
    int li = a0 & BMASK;
    long base = (long)(b * SCH) * (1 << BSH) + li;
    int4 s = {0, 0, 0, 0};
#pragma unroll
    for (int r = 0; r < SCH; ++r) {
        int4 p = *reinterpret_cast<const int4*>(partials + base + (long)r * (1 << BSH));
        s.x += p.x; s.y += p.y; s.z += p.z; s.w += p.w;
    }
    float4 qv = reinterpret_cast<const float4*>(Qa)[q];
    float4 sp = reinterpret_cast<const float4*>(out)[q];   // spill (or 0)
    float4 o;
    o.x = KEHALF * qv.x * ((float)s.x * VINV) + sp.x;
    o.y = KEHALF * qv.y * ((float)s.y * VINV) + sp.y;
    o.z = KEHALF * qv.z * ((float)s.z * VINV) + sp.z;
    o.w = KEHALF * qv.w * ((float)s.w * VINV) + sp.w;
    reinterpret_cast<float4*>(out)[q] = o;
}

// ---------------- Fallback: int fixed-point global atomics (R3) --------
#define FP_SCALE 4194304.0f
#define FP_INV   (1.0f / 4194304.0f)

__device__ __forceinline__ float radial_exact(float d) {
    float dsh = sqrtf(d * d + 1.0f);
    float x   = 0.5f * d;
    float sw  = (x < 1.0f) ? 1.0f - x * x * x * (x * (6.0f * x - 15.0f) + 10.0f)
                           : 0.0f;
    float Eo = 1.0f / d   + d   * 0.01f - 0.2f;
    float Es = 1.0f / dsh + dsh * 0.01f - 0.2f;
    return sw * Es + (1.0f - sw) * Eo;
}

__global__ __launch_bounds__(256) void ee_pair_fix(
    const float* __restrict__ Dij,
    const float* __restrict__ Qa,
    const int*   __restrict__ idx_i,
    const int*   __restrict__ idx_j,
    int*         __restrict__ acc,
    int P)
{
    long base = ((long)blockIdx.x * blockDim.x + threadIdx.x) * 4;
    if (base >= P) return;
    float4 d4 = *reinterpret_cast<const float4*>(Dij + base);
    int4   i4 = *reinterpret_cast<const int4*>(idx_i + base);
    int4   j4 = *reinterpret_cast<const int4*>(idx_j + base);
    float D[4]  = {d4.x, d4.y, d4.z, d4.w};
    int   ii[4] = {i4.x, i4.y, i4.z, i4.w};
    int   jj[4] = {j4.x, j4.y, j4.z, j4.w};
#pragma unroll
    for (int k = 0; k < 4; ++k) {
        float d = D[k];
        if (d > 10.0f) continue;
        float e = KEHALF * Qa[ii[k]] * Qa[jj[k]] * radial_exact(d);
        atomicAdd(acc + ii[k], __float2int_rn(e * FP_SCALE));
    }
}

__global__ __launch_bounds__(256) void ee_convert(
    const int* __restrict__ acc, float* __restrict__ out, int nAtoms)
{
    int n4 = nAtoms >> 2;
    int q = blockIdx.x * blockDim.x + threadIdx.x;
    if (q >= n4) return;
    int4 a = reinterpret_cast<const int4*>(acc)[q];
    float4 o;
    o.x = (float)a.x * FP_INV;
    o.y = (float)a.y * FP_INV;
    o.z = (float)a.z * FP_INV;
    o.w = (float)a.w * FP_INV;
    reinterpret_cast<float4*>(out)[q] = o;
}

__global__ __launch_bounds__(256) void ee_pair_direct(
    const float* __restrict__ Dij,
    const float* __restrict__ Qa,
    const int*   __restrict__ idx_i,
    const int*   __restrict__ idx_j,
    float*       __restrict__ out,
    int P)
{
    long t = (long)blockIdx.x * blockDim.x + threadIdx.x;
    if (t >= P) return;
    float d = Dij[t];
    if (d > 10.0f) return;
    atomicAdd(out + idx_i[t], KEHALF * Qa[idx_i[t]] * Qa[idx_j[t]] * radial_exact(d));
}

extern "C" void kernel_launch(void* const* d_in, const int* in_sizes, int n_in,
                              void* d_out, int out_size, void* d_ws, size_t ws_size,
                              hipStream_t stream) {
    const float* Dij   = (const float*)d_in[0];
    const float* Qa    = (const float*)d_in[1];
    const int*   idx_i = (const int*)d_in[2];
    const int*   idx_j = (const int*)d_in[3];
    float*       out   = (float*)d_out;

    int P      = in_sizes[0];
    int nAtoms = in_sizes[1];

    size_t listBytes = (size_t)NB * CAP * sizeof(unsigned int);          // 62 MiB
    size_t partBytes = (size_t)NB * SCH * (1 << BSH) * sizeof(int);      // 2 MiB
    size_t curBytes  = (size_t)NB * CURSTRIDE * sizeof(unsigned int);    // 8 KiB

    if (ws_size >= listBytes + partBytes + curBytes &&
        nAtoms == NB * (1 << BSH) && (P % P1PAIRS) == 0) {
        unsigned int* list = (unsigned int*)d_ws;
        int*          part = (int*)((char*)d_ws + listBytes);
        unsigned int* gcur = (unsigned int*)((char*)d_ws + listBytes + partBytes);
        hipMemsetAsync(gcur, 0, curBytes, stream);
        hipMemsetAsync(out, 0, (size_t)out_size * sizeof(float), stream); // spill base
        int grid1 = P / P1PAIRS;                                          // 2048
        ee_bin<<<grid1, P1B, 0, stream>>>(Dij, Qa, idx_i, idx_j, list, gcur, out);
        ee_acc<<<NB * SCH, 512, 0, stream>>>(list, gcur, part);
        ee_final<<<(nAtoms / 4 + 255) / 256, 256, 0, stream>>>(part, Qa, out, nAtoms);
    } else if (ws_size >= (size_t)nAtoms * sizeof(int) &&
               (nAtoms & 3) == 0 && (P & 3) == 0) {
        int* acc = (int*)d_ws;
        hipMemsetAsync(acc, 0, (size_t)nAtoms * sizeof(int), stream);
        int grid = (P / 4 + 255) / 256;
        ee_pair_fix<<<grid, 256, 0, stream>>>(Dij, Qa, idx_i, idx_j, acc, P);
        ee_convert<<<(nAtoms / 4 + 255) / 256, 256, 0, stream>>>(acc, out, nAtoms);
    } else {
        hipMemsetAsync(out, 0, (size_t)out_size * sizeof(float), stream);
        int grid = (P + 255) / 256;
        ee_pair_direct<<<grid, 256, 0, stream>>>(Dij, Qa, idx_i, idx_j, out, P);
    }
}